// Round 4
// baseline (49120.868 us; speedup 1.0000x reference)
//
#include <hip/hip_runtime.h>
#include <hip/hip_bf16.h>

#define EMBD 300
#define GG   4096
#define NLAY 5
#define KP1  320   // padded K for EMB=300 inputs
#define KP2  640   // padded K for 2*EMB=600 inputs
#define NP1  640   // padded B-rows / out-cols for 600
#define NP2  384   // padded B-rows for 300-col GEMM2 (multiple of 128)

typedef unsigned short ushort_t;
typedef short short8 __attribute__((ext_vector_type(8)));
typedef short short4v __attribute__((ext_vector_type(4)));
typedef float f32x4 __attribute__((ext_vector_type(4)));

static inline int cdiv(int a, int b) { return (a + b - 1) / b; }

// ---------------- helpers ----------------

__device__ inline void dma16(const ushort_t* g, ushort_t* l) {
    __builtin_amdgcn_global_load_lds(
        (const __attribute__((address_space(1))) unsigned int*)g,
        (__attribute__((address_space(3))) unsigned int*)l, 16, 0, 0);
}

__device__ inline void bf16_split(float v, ushort_t& h, ushort_t& l) {
    union { __hip_bfloat16 b; ushort_t u; } c;
    c.b = __float2bfloat16(v);
    h = c.u;
    float hf = __bfloat162float(c.b);
    c.b = __float2bfloat16(v - hf);
    l = c.u;
}

// ---------------- elementwise kernels ----------------

__global__ void atom_encode4(const int* __restrict__ x, const float* __restrict__ aemb,
                             float* __restrict__ h, int N) {
    int i = blockIdx.x * blockDim.x + threadIdx.x;
    int total = N * 75;
    if (i >= total) return;
    int n = i / 75, d4 = i - n * 75;
    const int* xr = x + n * 9;
    float4 s = make_float4(0.f, 0.f, 0.f, 0.f);
    const float4* a4 = (const float4*)aemb;
#pragma unroll
    for (int f = 0; f < 9; ++f) {
        float4 v = a4[(size_t)((f << 7) + xr[f]) * 75 + d4];
        s.x += v.x; s.y += v.y; s.z += v.z; s.w += v.w;
    }
    ((float4*)h)[i] = s;
}

__global__ void init_vn4(const float* __restrict__ vn_emb, float* __restrict__ vn) {
    int i = blockIdx.x * blockDim.x + threadIdx.x;
    if (i >= GG * 75) return;
    ((float4*)vn)[i] = ((const float4*)vn_emb)[i % 75];
}

__global__ void find_starts(const int* __restrict__ batch, int* __restrict__ starts, int N) {
    int g = blockIdx.x * blockDim.x + threadIdx.x;
    if (g > GG) return;
    int lo = 0, hi = N;
    while (lo < hi) {
        int mid = (lo + hi) >> 1;
        if (batch[mid] < g) lo = mid + 1; else hi = mid;
    }
    starts[g] = lo;
}

// h += vn[batch]  (in place)
__global__ void prep_vn(float* __restrict__ h, const float* __restrict__ vn,
                        const int* __restrict__ batch, int N) {
    int i = blockIdx.x * blockDim.x + threadIdx.x;
    int total = N * 75;
    if (i >= total) return;
    int n = i / 75, d4 = i - n * 75;
    float4 hv = ((const float4*)h)[i];
    float4 vv = ((const float4*)vn)[(size_t)batch[n] * 75 + d4];
    hv.x += vv.x; hv.y += vv.y; hv.z += vv.z; hv.w += vv.w;
    ((float4*)h)[i] = hv;
}

__global__ void pool_graphs(const float* __restrict__ h, const int* __restrict__ starts,
                            float* __restrict__ pooled) {
    int g = blockIdx.x;
    int t = threadIdx.x;
    if (t >= EMBD) return;
    int s0 = starts[g], s1 = starts[g + 1];
    float s = 0.f;
    for (int n = s0; n < s1; ++n) s += h[(size_t)n * EMBD + t];
    pooled[(size_t)g * EMBD + t] = s;
}

__global__ void pool_mean(const float* __restrict__ h, const int* __restrict__ starts,
                          float* __restrict__ out) {
    int g = blockIdx.x;
    int t = threadIdx.x;
    if (t >= EMBD) return;
    int s0 = starts[g], s1 = starts[g + 1];
    float s = 0.f;
    for (int n = s0; n < s1; ++n) s += h[(size_t)n * EMBD + t];
    float cnt = (float)(s1 - s0);
    out[(size_t)g * EMBD + t] = s / fmaxf(cnt, 1.0f);
}

// ---------------- edge bucket sort (once per launch) ----------------

__global__ void ecount(const int* __restrict__ ei, int* __restrict__ cnt, int E) {
    int e = blockIdx.x * blockDim.x + threadIdx.x;
    if (e >= E) return;
    atomicAdd(&cnt[ei[E + e]], 1);
}

__global__ void scan_counts(const int* __restrict__ cnt, int* __restrict__ estart,
                            int* __restrict__ cursor, int N, int E) {
    __shared__ int part[1024];
    int tid = threadIdx.x;
    int vpt = (N + 1023) >> 10;
    int lo = tid * vpt, hi = lo + vpt;
    if (hi > N) hi = N;
    int s = 0;
    for (int j = lo; j < hi; ++j) s += cnt[j];
    part[tid] = s;
    __syncthreads();
    for (int d = 1; d < 1024; d <<= 1) {
        int v = (tid >= d) ? part[tid - d] : 0;
        __syncthreads();
        part[tid] += v;
        __syncthreads();
    }
    int run = part[tid] - s;   // exclusive prefix for this thread's chunk
    for (int j = lo; j < hi; ++j) { estart[j] = run; cursor[j] = run; run += cnt[j]; }
    if (tid == 0) estart[N] = E;
}

__global__ void escatter(const int* __restrict__ ei, int* __restrict__ cursor,
                         int* __restrict__ ebucket, int E) {
    int e = blockIdx.x * blockDim.x + threadIdx.x;
    if (e >= E) return;
    int c = ei[E + e];
    int p = atomicAdd(&cursor[c], 1);
    ebucket[p] = e;
}

// ---------------- fused aggregate: (1+eps)h + sum relu(h[row]+bond) -> split bf16 ----------------
#define NPB 4   // nodes per block; blockDim = NPB*80 = 320

__global__ void aggregate(const float* __restrict__ h, const int* __restrict__ ei,
                          const int* __restrict__ ea, const float* __restrict__ bemb,
                          const int* __restrict__ estart, const int* __restrict__ ebucket,
                          const float* __restrict__ epsp,
                          ushort_t* __restrict__ aggH, ushort_t* __restrict__ aggL,
                          int N, int E) {
    int n = blockIdx.x * NPB + threadIdx.x / 80;
    int slot = threadIdx.x % 80;
    if (n >= N) return;
    float4 acc = make_float4(0.f, 0.f, 0.f, 0.f);
    if (slot < 75) {
        const float4* h4 = (const float4*)h;
        const float4* b4 = (const float4*)bemb;
        float ce = 1.0f + *epsp;
        float4 hv = h4[(size_t)n * 75 + slot];
        acc = make_float4(ce * hv.x, ce * hv.y, ce * hv.z, ce * hv.w);
        int p0 = estart[n], p1 = estart[n + 1];
        for (int p = p0; p < p1; ++p) {
            int e = ebucket[p];
            int r = ei[e];
            int a0 = ea[3 * e], a1 = ea[3 * e + 1], a2 = ea[3 * e + 2];
            float4 xv = h4[(size_t)r * 75 + slot];
            float4 e0 = b4[(size_t)a0 * 75 + slot];
            float4 e1 = b4[(size_t)(8 + a1) * 75 + slot];
            float4 e2 = b4[(size_t)(16 + a2) * 75 + slot];
            acc.x += fmaxf(xv.x + e0.x + e1.x + e2.x, 0.f);
            acc.y += fmaxf(xv.y + e0.y + e1.y + e2.y, 0.f);
            acc.z += fmaxf(xv.z + e0.z + e1.z + e2.z, 0.f);
            acc.w += fmaxf(xv.w + e0.w + e1.w + e2.w, 0.f);
        }
    }
    float vals[4] = {acc.x, acc.y, acc.z, acc.w};
    short4v hv4, lv4;
#pragma unroll
    for (int j = 0; j < 4; ++j) {
        ushort_t hh, ll;
        bf16_split(vals[j], hh, ll);
        hv4[j] = (short)hh;
        lv4[j] = (short)ll;
    }
    size_t o = (size_t)n * KP1 + slot * 4;
    *(short4v*)(aggH + o) = hv4;
    *(short4v*)(aggL + o) = lv4;
}

// ---------------- split / transpose kernels ----------------

// in [M][Kreal] fp32 (+optional add2) -> H,L ushort [M][KP], zero-padded
__global__ void conv_split(const float* __restrict__ in, const float* __restrict__ add2,
                           ushort_t* __restrict__ H, ushort_t* __restrict__ L,
                           int M, int Kreal, int KP) {
    int i = blockIdx.x * blockDim.x + threadIdx.x;
    int total = M * KP;
    if (i >= total) return;
    int r = i / KP, k = i - r * KP;
    float v = 0.f;
    if (k < Kreal) {
        v = in[(size_t)r * Kreal + k];
        if (add2) v += add2[(size_t)r * Kreal + k];
    }
    ushort_t hh, ll;
    bf16_split(v, hh, ll);
    H[i] = hh;
    L[i] = ll;
}

// W [K][Nn] fp32 -> HT,LT ushort [NnP][KP] (transposed, zero-padded)
__global__ void conv_wT(const float* __restrict__ W, ushort_t* __restrict__ HT,
                        ushort_t* __restrict__ LT, int K, int Nn, int KP, int NnP) {
    int i = blockIdx.x * blockDim.x + threadIdx.x;
    int total = NnP * KP;
    if (i >= total) return;
    int n = i / KP, k = i - n * KP;
    float v = (n < Nn && k < K) ? W[(size_t)k * Nn + n] : 0.f;
    ushort_t hh, ll;
    bf16_split(v, hh, ll);
    HT[i] = hh;
    LT[i] = ll;
}

// ---------------- split-bf16 MFMA GEMM, 128x128 tile, 2-stage LDS pipeline ----------------
#define BMg 128
#define BNg 128

__global__ __launch_bounds__(256) void gemm_split(
    const ushort_t* __restrict__ AH, const ushort_t* __restrict__ AL, int KP,
    const ushort_t* __restrict__ BH, const ushort_t* __restrict__ BL,
    const float* __restrict__ bias, const float* __restrict__ gg,
    const float* __restrict__ bb, const float* __restrict__ bm,
    const float* __restrict__ bv,
    int Mc, int NnReal, int relu,
    float* __restrict__ outF, int ldF,
    ushort_t* __restrict__ outH, ushort_t* __restrict__ outL, int ldP)
{
    // 64 KB total: 2 stages x (A 16KB + B 16KB), H/L halves
    __shared__ ushort_t sAH[2][BMg * 32];
    __shared__ ushort_t sAL[2][BMg * 32];
    __shared__ ushort_t sBH[2][BNg * 32];
    __shared__ ushort_t sBL[2][BNg * 32];

    const int tid = threadIdx.x;
    const int lane = tid & 63;
    const int w = tid >> 6;
    const int m0 = blockIdx.y * BMg;
    const int n0 = blockIdx.x * BNg;
    const int wm = (w & 1) * 64;
    const int wn = (w >> 1) * 64;

    // DMA slots: s = row*4 + q'; q' = (q + (row>>1)) & 3 swizzle. 512 slots per array,
    // thread covers slots tid and tid+256. LDS base must be wave-uniform.
    const ushort_t* gAH[2]; const ushort_t* gAL[2];
    const ushort_t* gBH[2]; const ushort_t* gBL[2];
    int lbase[2];
#pragma unroll
    for (int i = 0; i < 2; ++i) {
        int s = tid + 256 * i;
        int m = s >> 2, qp = s & 3;
        int q = (qp - (m >> 1)) & 3;
        int msrc = m0 + m; if (msrc >= Mc) msrc = Mc - 1;
        gAH[i] = AH + (size_t)msrc * KP + 8 * q;
        gAL[i] = AL + (size_t)msrc * KP + 8 * q;
        int nsrc = n0 + m;   // B rows fully padded, no clamp needed
        gBH[i] = BH + (size_t)nsrc * KP + 8 * q;
        gBL[i] = BL + (size_t)nsrc * KP + 8 * q;
        lbase[i] = (w * 64 + 256 * i) * 8;
    }

    f32x4 acc[4][4];
#pragma unroll
    for (int a = 0; a < 4; ++a)
#pragma unroll
        for (int b = 0; b < 4; ++b) acc[a][b] = (f32x4)(0.f);

    const int q = lane >> 4;
    const int c16 = lane & 15;
    const int kt = KP >> 5;

    // prefetch tile 0 -> stage 0
#pragma unroll
    for (int i = 0; i < 2; ++i) {
        dma16(gAH[i], sAH[0] + lbase[i]); gAH[i] += 32;
        dma16(gAL[i], sAL[0] + lbase[i]); gAL[i] += 32;
        dma16(gBH[i], sBH[0] + lbase[i]); gBH[i] += 32;
        dma16(gBL[i], sBL[0] + lbase[i]); gBL[i] += 32;
    }
    __syncthreads();

    for (int t = 0; t < kt; ++t) {
        int cur = t & 1, nxt = cur ^ 1;
        if (t + 1 < kt) {
#pragma unroll
            for (int i = 0; i < 2; ++i) {
                dma16(gAH[i], sAH[nxt] + lbase[i]); gAH[i] += 32;
                dma16(gAL[i], sAL[nxt] + lbase[i]); gAL[i] += 32;
                dma16(gBH[i], sBH[nxt] + lbase[i]); gBH[i] += 32;
                dma16(gBL[i], sBL[nxt] + lbase[i]); gBL[i] += 32;
            }
        }
        short8 ah[4], al[4], bh[4], bl[4];
#pragma unroll
        for (int tt = 0; tt < 4; ++tt) {
            int m = wm + tt * 16 + c16;
            int q2 = (q + (m >> 1)) & 3;
            int off = m * 32 + q2 * 8;
            ah[tt] = *(const short8*)(sAH[cur] + off);
            al[tt] = *(const short8*)(sAL[cur] + off);
        }
#pragma unroll
        for (int uu = 0; uu < 4; ++uu) {
            int n = wn + uu * 16 + c16;
            int q2 = (q + (n >> 1)) & 3;
            int off = n * 32 + q2 * 8;
            bh[uu] = *(const short8*)(sBH[cur] + off);
            bl[uu] = *(const short8*)(sBL[cur] + off);
        }
#pragma unroll
        for (int tt = 0; tt < 4; ++tt)
#pragma unroll
            for (int uu = 0; uu < 4; ++uu) {
                acc[tt][uu] = __builtin_amdgcn_mfma_f32_16x16x32_bf16(ah[tt], bh[uu], acc[tt][uu], 0, 0, 0);
                acc[tt][uu] = __builtin_amdgcn_mfma_f32_16x16x32_bf16(ah[tt], bl[uu], acc[tt][uu], 0, 0, 0);
                acc[tt][uu] = __builtin_amdgcn_mfma_f32_16x16x32_bf16(al[tt], bh[uu], acc[tt][uu], 0, 0, 0);
            }
        __syncthreads();
    }

    // epilogue: C/D layout col=lane&15, row=q*4+r
#pragma unroll
    for (int uu = 0; uu < 4; ++uu) {
        int gn = n0 + wn + uu * 16 + c16;
        float sc = 0.f, sh = 0.f;
        if (gn < NnReal) {
            sc = gg[gn] * rsqrtf(bv[gn] + 1e-5f);
            sh = bb[gn] + (bias[gn] - bm[gn]) * sc;
        }
#pragma unroll
        for (int tt = 0; tt < 4; ++tt) {
            int rbase = m0 + wm + tt * 16 + q * 4;
#pragma unroll
            for (int r = 0; r < 4; ++r) {
                int gm = rbase + r;
                if (gm >= Mc) continue;
                float y = acc[tt][uu][r] * sc + sh;
                if (relu) y = fmaxf(y, 0.f);
                if (outF) {
                    if (gn < NnReal) outF[(size_t)gm * ldF + gn] = y;
                } else {
                    if (gn < ldP) {
                        ushort_t hh, ll;
                        bf16_split(y, hh, ll);
                        outH[(size_t)gm * ldP + gn] = hh;
                        outL[(size_t)gm * ldP + gn] = ll;
                    }
                }
            }
        }
    }
}

// ---------------- host-side MLP ----------------

struct MlpW {
    const float *W1, *b1, *g1, *be1, *m1, *v1;
    const float *W2, *b2, *g2, *be2, *m2, *v2;
};

// inputs already split: inH/inL [M][KP1] -> outF fp32 [M][300]
static void run_mlp(hipStream_t stream, const ushort_t* inH, const ushort_t* inL, int M,
                    ushort_t* w1h, ushort_t* w1l, ushort_t* w2h, ushort_t* w2l,
                    ushort_t* tH, ushort_t* tL, int CH,
                    const MlpW& W, float* outF, int relu2) {
    const int BLK = 256;
    conv_wT<<<cdiv(NP1 * KP1, BLK), BLK, 0, stream>>>(W.W1, w1h, w1l, EMBD, 2 * EMBD, KP1, NP1);
    conv_wT<<<cdiv(NP2 * KP2, BLK), BLK, 0, stream>>>(W.W2, w2h, w2l, 2 * EMBD, EMBD, KP2, NP2);
    for (int c0 = 0; c0 < M; c0 += CH) {
        int Mc = (M - c0 < CH) ? (M - c0) : CH;
        {
            dim3 grid(NP1 / BNg, cdiv(Mc, BMg));
            gemm_split<<<grid, 256, 0, stream>>>(
                inH + (size_t)c0 * KP1, inL + (size_t)c0 * KP1, KP1, w1h, w1l,
                W.b1, W.g1, W.be1, W.m1, W.v1,
                Mc, 2 * EMBD, 1,
                nullptr, 0, tH, tL, KP2);
        }
        {
            dim3 grid(NP2 / BNg, cdiv(Mc, BMg));
            gemm_split<<<grid, 256, 0, stream>>>(
                tH, tL, KP2, w2h, w2l,
                W.b2, W.g2, W.be2, W.m2, W.v2,
                Mc, EMBD, relu2,
                outF + (size_t)c0 * EMBD, EMBD, nullptr, nullptr, 0);
        }
    }
}

// ---------------- entry ----------------

extern "C" void kernel_launch(void* const* d_in, const int* in_sizes, int n_in,
                              void* d_out, int out_size, void* d_ws, size_t ws_size,
                              hipStream_t stream) {
    const int*   x        = (const int*)d_in[0];
    const int*   ei       = (const int*)d_in[1];
    const int*   ea       = (const int*)d_in[2];
    const int*   batch    = (const int*)d_in[3];
    const float* atom_emb = (const float*)d_in[4];
    const float* bond_emb = (const float*)d_in[5];
    const float* vn_emb   = (const float*)d_in[6];
    const float* gin_eps  = (const float*)d_in[7];
    const float* gin_W1   = (const float*)d_in[8];
    const float* gin_b1   = (const float*)d_in[9];
    const float* gin_bn1g = (const float*)d_in[10];
    const float* gin_bn1b = (const float*)d_in[11];
    const float* gin_bn1m = (const float*)d_in[12];
    const float* gin_bn1v = (const float*)d_in[13];
    const float* gin_W2   = (const float*)d_in[14];
    const float* gin_b2   = (const float*)d_in[15];
    const float* bn_g     = (const float*)d_in[16];
    const float* bn_b     = (const float*)d_in[17];
    const float* bn_m     = (const float*)d_in[18];
    const float* bn_v     = (const float*)d_in[19];
    const float* vn_W1    = (const float*)d_in[20];
    const float* vn_b1    = (const float*)d_in[21];
    const float* vn_bn1g  = (const float*)d_in[22];
    const float* vn_bn1b  = (const float*)d_in[23];
    const float* vn_bn1m  = (const float*)d_in[24];
    const float* vn_bn1v  = (const float*)d_in[25];
    const float* vn_W2    = (const float*)d_in[26];
    const float* vn_b2    = (const float*)d_in[27];
    const float* vn_bn2g  = (const float*)d_in[28];
    const float* vn_bn2b  = (const float*)d_in[29];
    const float* vn_bn2m  = (const float*)d_in[30];
    const float* vn_bn2v  = (const float*)d_in[31];

    const int N = in_sizes[3];
    const int E = in_sizes[1] / 2;

    // ---- workspace layout (bytes); fixed ~268 MB ----
    char* base = (char*)d_ws;
    size_t off = 0;
    float* hbuf   = (float*)(base + off); off += (size_t)N * EMBD * 4;
    ushort_t* aggH = (ushort_t*)(base + off); off += (size_t)N * KP1 * 2;
    ushort_t* aggL = (ushort_t*)(base + off); off += (size_t)N * KP1 * 2;
    float* vnbuf  = (float*)(base + off); off += (size_t)GG * EMBD * 4;
    float* pooled = (float*)(base + off); off += (size_t)GG * EMBD * 4;
    int*   starts = (int*)(base + off);   off += 4104 * 4;
    int*   cnt    = (int*)(base + off);   off += (size_t)N * 4;
    int*   cursor = (int*)(base + off);   off += (size_t)N * 4;
    int*   estart = (int*)(base + off);   off += ((size_t)N + 8) * 4;
    int*   ebucket= (int*)(base + off);   off += (size_t)E * 4;
    ushort_t* w1h = (ushort_t*)(base + off); off += (size_t)NP1 * KP1 * 2;
    ushort_t* w1l = (ushort_t*)(base + off); off += (size_t)NP1 * KP1 * 2;
    ushort_t* w2h = (ushort_t*)(base + off); off += (size_t)NP2 * KP2 * 2;
    ushort_t* w2l = (ushort_t*)(base + off); off += (size_t)NP2 * KP2 * 2;
    ushort_t* vnaH = (ushort_t*)(base + off); off += (size_t)GG * KP1 * 2;
    ushort_t* vnaL = (ushort_t*)(base + off); off += (size_t)GG * KP1 * 2;
    off = (off + 255) & ~(size_t)255;

    // adaptive chunk for tH/tL: 2560 B per row
    size_t avail = (ws_size > off) ? ws_size - off : 0;
    int CH = (int)(avail / 2560);
    CH &= ~127;
    if (CH > N) CH = (N + 127) & ~127;
    if (CH < 128) CH = 128;  // last resort
    ushort_t* tH = (ushort_t*)(base + off);
    ushort_t* tL = tH + (size_t)CH * KP2;

    const int BLK = 256;
    int ne4 = N * 75;

    // init + edge bucket sort (edges are layer-invariant)
    find_starts<<<cdiv(GG + 1, BLK), BLK, 0, stream>>>(batch, starts, N);
    atom_encode4<<<cdiv(ne4, BLK), BLK, 0, stream>>>(x, atom_emb, hbuf, N);
    init_vn4<<<cdiv(GG * 75, BLK), BLK, 0, stream>>>(vn_emb, vnbuf);
    hipMemsetAsync(cnt, 0, (size_t)N * 4, stream);
    ecount<<<cdiv(E, BLK), BLK, 0, stream>>>(ei, cnt, E);
    scan_counts<<<1, 1024, 0, stream>>>(cnt, estart, cursor, N, E);
    escatter<<<cdiv(E, BLK), BLK, 0, stream>>>(ei, cursor, ebucket, E);

    for (int l = 0; l < NLAY; ++l) {
        int last = (l == NLAY - 1);

        prep_vn<<<cdiv(ne4, BLK), BLK, 0, stream>>>(hbuf, vnbuf, batch, N);
        if (!last)
            pool_graphs<<<GG, 320, 0, stream>>>(hbuf, starts, pooled);

        aggregate<<<cdiv(N, NPB), NPB * 80, 0, stream>>>(
            hbuf, ei, ea, bond_emb, estart, ebucket, gin_eps + l, aggH, aggL, N, E);

        MlpW Wn = { gin_W1 + (size_t)l * EMBD * 2 * EMBD, gin_b1 + (size_t)l * 2 * EMBD,
                    gin_bn1g + (size_t)l * 2 * EMBD, gin_bn1b + (size_t)l * 2 * EMBD,
                    gin_bn1m + (size_t)l * 2 * EMBD, gin_bn1v + (size_t)l * 2 * EMBD,
                    gin_W2 + (size_t)l * 2 * EMBD * EMBD, gin_b2 + (size_t)l * EMBD,
                    bn_g + (size_t)l * EMBD, bn_b + (size_t)l * EMBD,
                    bn_m + (size_t)l * EMBD, bn_v + (size_t)l * EMBD };
        run_mlp(stream, aggH, aggL, N, w1h, w1l, w2h, w2l, tH, tL, CH,
                Wn, hbuf, last ? 0 : 1);

        if (!last) {
            conv_split<<<cdiv(GG * KP1, BLK), BLK, 0, stream>>>(
                pooled, vnbuf, vnaH, vnaL, GG, EMBD, KP1);
            MlpW Wv = { vn_W1 + (size_t)l * EMBD * 2 * EMBD, vn_b1 + (size_t)l * 2 * EMBD,
                        vn_bn1g + (size_t)l * 2 * EMBD, vn_bn1b + (size_t)l * 2 * EMBD,
                        vn_bn1m + (size_t)l * 2 * EMBD, vn_bn1v + (size_t)l * 2 * EMBD,
                        vn_W2 + (size_t)l * 2 * EMBD * EMBD, vn_b2 + (size_t)l * EMBD,
                        vn_bn2g + (size_t)l * EMBD, vn_bn2b + (size_t)l * EMBD,
                        vn_bn2m + (size_t)l * EMBD, vn_bn2v + (size_t)l * EMBD };
            run_mlp(stream, vnaH, vnaL, GG, w1h, w1l, w2h, w2l, tH, tL, CH,
                    Wv, vnbuf, 1);
        }
    }

    pool_mean<<<GG, 320, 0, stream>>>(hbuf, starts, (float*)d_out);
}